// Round 11
// baseline (41.379 us; speedup 1.0000x reference)
//
#include <hip/hip_runtime.h>
#include <math.h>

namespace {

constexpr int K_   = 9;
constexpr int NC_  = 13;
constexpr int NA_  = 5;
constexpr int NL_  = 21;      // 2K+3
constexpr int NB_  = 32;
constexpr int NH_  = 32;
constexpr int NW_  = 32;
constexpr int NPIX = NH_ * NW_;     // 1024
constexpr int M_   = NA_ * NPIX;    // 5120
constexpr int N_   = NB_ * M_;      // 163840
constexpr int NT_  = 50;
constexpr int CH_  = 2 * K_ + 1 + NC_;  // 32 channels per anchor
constexpr int BLK  = 256;
constexpr int SUBS = M_ / BLK;      // 20 blocks per batch
constexpr int NBLK = NB_ * SUBS;    // 640

constexpr float TH_    = 30.0f;
constexpr float SHARP_ = 2.0f;
constexpr float IMW_   = 640.0f;
constexpr float IMH_   = 480.0f;
constexpr float EPS_   = 1e-5f;
constexpr float OBJ_   = 5.0f;

constexpr float L2E_  = 1.4426950408889634f;
constexpr float CC1_  = -(SHARP_ / TH_) * L2E_;   // slope per pixel-distance, log2 domain
constexpr float CC2_  = SHARP_ * L2E_;            // offset, log2 domain
// 0.6 * ((e^2-1)+eps) * 9 : sum-domain silence threshold.
// A target with 2-D close-count c has sum <= c*(e^2-1)=6.389c; c<=5 -> 31.95 < 34.50,
// so only targets with 2-D cnt>=6 can trip (cur > SIL).
constexpr float SUMTHR_ = 34.500957f;
constexpr float WSLACK_ = TH_ + 4.0f;   // window slack: 30 + fp/half-rounding margin

typedef _Float16 h2v __attribute__((ext_vector_type(2)));

__device__ __constant__ float c_aw[5] = {1.482f, 2.0501f, 2.3946f, 3.1018f, 3.4879f};
__device__ __constant__ float c_ah[5] = {2.2412f, 3.1265f, 4.6891f, 3.991f, 5.2505f};

__device__ __forceinline__ float sigm(float x) {
    return 1.0f / (1.0f + __builtin_amdgcn_exp2f(-L2E_ * x));
}

// corner-conf term, pixel-domain d2: exp(SHARP*(1-d/TH)) - 1, masked to d<TH
__device__ __forceinline__ float conf_term_px(float d2) {
    float e = __builtin_amdgcn_exp2f(fmaf(__builtin_amdgcn_sqrtf(d2), CC1_, CC2_)) - 1.0f;
    return (d2 < TH_ * TH_) ? e : 0.0f;
}

__device__ __forceinline__ h2v h2min(h2v a, h2v b) {
#if __has_builtin(__builtin_elementwise_min)
    return __builtin_elementwise_min(a, b);
#else
    h2v r;
    r[0] = a[0] < b[0] ? a[0] : b[0];
    r[1] = a[1] < b[1] ? a[1] : b[1];
    return r;
#endif
}

// ------------- Single kernel: targets + screen + losses + fenced reduce -------
__global__ __launch_bounds__(BLK) void k_fused(
        const float* __restrict__ outp,
        const float* __restrict__ tgt,
        const int*   __restrict__ epoch,
        float* __restrict__ loss,
        float* __restrict__ partial,
        unsigned int* __restrict__ counter)
{
    __shared__ float s_t[NT_ * NL_];    // whole target slab for this batch
    __shared__ int   s_win[BLK];
    __shared__ int   s_nv;
    __shared__ float s_red[8];
    __shared__ int   s_last;

    int bx  = blockIdx.x;
    int b   = bx / SUBS, sub = bx - b * SUBS;
    int tid = threadIdx.x;
    int lane = tid & 63;

    const float* tb = tgt + (size_t)b * NT_ * NL_;
    s_win[tid] = -1;
    for (int i = tid; i < NT_ * NL_; i += BLK) s_t[i] = tb[i];
    __syncthreads();

    if (tid < 64) {   // wave 0: validity prefix via ballot
        float x0 = (tid < NT_) ? s_t[tid * NL_ + 1] : 0.0f;
        unsigned long long mk = __ballot(tid < NT_ && x0 != 0.0f);
        if (tid == 0) s_nv = (int)__builtin_ctzll((~mk) | (1ull << NT_));
    }
    __syncthreads();
    int nv = s_nv;

    // per-target flat + win scatter (recomputed per block; 50 lanes, cheap)
    if (tid < nv) {
        const float* row = &s_t[tid * NL_];
        int gi0 = (int)(row[1] * (float)NW_);
        int gj0 = (int)(row[2] * (float)NH_);
        float gw = row[NL_ - 2] * (float)NW_;
        float gh = row[NL_ - 1] * (float)NH_;
        float best_iou = 0.0f; int best_n = -1;
#pragma unroll
        for (int a = 0; a < NA_; ++a) {
            float cw  = fminf(c_aw[a], gw);
            float chh = fminf(c_ah[a], gh);
            float iou = 0.0f;
            if (cw > 0.0f && chh > 0.0f) {
                float inter = cw * chh;
                iou = inter / (c_aw[a] * c_ah[a] + gw * gh - inter);
            }
            if (iou > best_iou) { best_iou = iou; best_n = a; }
        }
        int bn = ((best_n % NA_) + NA_) % NA_;   // Python -1 % 5 == 4
        int flat = ((b * NA_ + bn) * NH_ + gj0) * NW_ + gi0;
        int rel = flat - b * M_ - sub * BLK;
        if (rel >= 0 && rel < BLK) atomicMax(&s_win[rel], tid);  // last(=max) t wins
    }
    __syncthreads();

    int m = sub * BLK + tid;
    int a = m / NPIX;  int pix = m - a * NPIX;   // a uniform per block (BLK | NPIX)
    int h = pix >> 5;  int w   = pix & 31;
    const float* cb = outp + ((size_t)(b * NA_ + a)) * CH_ * NPIX + pix;

    // y channels (raw kept for hit path), qy in pixel domain
    float ysv[K_], qy[K_];
    ysv[0] = sigm(cb[NPIX]);
#pragma unroll
    for (int k = 1; k < K_; ++k) ysv[k] = cb[(size_t)(k + 3) * NPIX];
#pragma unroll
    for (int k = 0; k < K_; ++k) qy[k] = (ysv[k] + (float)h) * (IMH_ / NH_);

    // per-wave min/max of qy[k]: packed-half butterfly (mn, -mx) via pk_min
    h2v pk[K_];
#pragma unroll
    for (int k = 0; k < K_; ++k) {
        pk[k][0] = (_Float16)qy[k];
        pk[k][1] = (_Float16)(-qy[k]);
    }
#pragma unroll
    for (int off = 1; off < 64; off <<= 1) {
#pragma unroll
        for (int k = 0; k < K_; ++k) {
            unsigned u; __builtin_memcpy(&u, &pk[k], 4);
            u = __shfl_xor(u, off);
            h2v o; __builtin_memcpy(&o, &u, 4);
            pk[k] = h2min(pk[k], o);
        }
    }
    float mnw[K_], mxw[K_];
#pragma unroll
    for (int k = 0; k < K_; ++k) {
        mnw[k] = (float)pk[k][0] - WSLACK_;
        mxw[k] = -(float)pk[k][1] + WSLACK_;
    }

    // layer 1: wave-uniform survivor ballot (lane t checks target t)
    int wcnt = 0;
    if (lane < NT_) {
        const float* tr = &s_t[lane * NL_];
#pragma unroll
        for (int k = 0; k < K_; ++k) {
            float gy = tr[2 + 2 * k] * IMH_;
            wcnt += (gy >= mnw[k] && gy <= mxw[k]) ? 1 : 0;
        }
    }
    unsigned long long smask = __ballot(lane < NT_ && wcnt >= 6);
    smask &= (nv >= 64) ? ~0ull : ((1ull << nv) - 1);   // valid-prefix targets only

    // layer 2: per-lane y-cnt>=6 over survivors -> per-lane candidate mask
    unsigned long long candm = 0;
    unsigned long long mm = smask;
    while (mm) {
        int t = (int)__builtin_ctzll(mm); mm &= mm - 1;
        const float* tr = &s_t[t * NL_];   // uniform addr -> LDS broadcast
        int cnt = 0;
#pragma unroll
        for (int k = 0; k < K_; ++k) {
            float dy = tr[2 + 2 * k] * IMH_ - qy[k];
            cnt += (fabsf(dy) < TH_) ? 1 : 0;
        }
        if (cnt >= 6) candm |= 1ull << t;
    }

    float cm0 = 1.0f;
    if (candm) {   // ~1% of lanes: 2-D refine, then (astronomically rare) exact
        float qx[K_];
        qx[0] = (sigm(cb[0]) + (float)w) * (IMW_ / NW_);
#pragma unroll
        for (int k = 1; k < K_; ++k)
            qx[k] = (cb[(size_t)(k + 2) * NPIX] + (float)w) * (IMW_ / NW_);

        unsigned long long hot = 0, m2 = candm;
        while (m2) {
            int t = (int)__builtin_ctzll(m2); m2 &= m2 - 1;
            const float* tr = &s_t[t * NL_];
            int cnt = 0;
#pragma unroll
            for (int k = 0; k < K_; ++k) {
                float dx = tr[1 + 2 * k] * IMW_ - qx[k];
                float dy = tr[2 + 2 * k] * IMH_ - qy[k];
                float d2 = fmaf(dx, dx, dy * dy);
                cnt += (d2 < TH_ * TH_) ? 1 : 0;
            }
            if (cnt >= 6) hot |= 1ull << t;
        }
        if (hot) {   // exact sum only over targets that can possibly trip SIL
            float ms = 0.0f;
            while (hot) {
                int t = (int)__builtin_ctzll(hot); hot &= hot - 1;
                const float* tr = &s_t[t * NL_];
                float s = 0.0f;
#pragma unroll
                for (int k = 0; k < K_; ++k) {
                    float dx = tr[1 + 2 * k] * IMW_ - qx[k];
                    float dy = tr[2 + 2 * k] * IMH_ - qy[k];
                    s += conf_term_px(fmaf(dx, dx, dy * dy));
                }
                ms = fmaxf(ms, s);
            }
            cm0 = (ms > SUMTHR_) ? 0.0f : 1.0f;
        }
    }

    // per-cell losses
    float cf = sigm(cb[(size_t)(2 * K_) * NPIX]);   // channel 18
    int win = s_win[tid];
    float acc_main = 0.0f, acc_conf = 0.0f;
    if (win >= 0) {                                  // hit path (~2.5 lanes/block)
        const float* trw = &s_t[win * NL_];
        int gi0 = (int)(trw[1] * (float)NW_);
        int gj0 = (int)(trw[2] * (float)NH_);

        float xsv[K_];
        xsv[0] = sigm(cb[0]);
#pragma unroll
        for (int k = 1; k < K_; ++k) xsv[k] = cb[(size_t)(k + 2) * NPIX];

        float lxy = 0.0f;
#pragma unroll
        for (int k = 0; k < K_; ++k) {
            float tx = trw[1 + 2 * k] * (float)NW_ - (float)gi0;
            float ty = trw[2 + 2 * k] * (float)NH_ - (float)gj0;
            float ddx = xsv[k] - tx;
            float ddy = ysv[k] - ty;
            lxy += ddx * ddx + ddy * ddy;
        }

        // conf_t: gather prediction at pb = (b*M - nPix + gj0*nW + gi0) mod N
        long long pbl = (long long)b * M_ - NPIX + gj0 * NW_ + gi0;
        int pb = (int)(((pbl % N_) + N_) % N_);
        int b2 = pb / M_;   int m2i  = pb - b2 * M_;
        int a2 = m2i / NPIX; int pix2 = m2i - a2 * NPIX;
        int h2 = pix2 / NW_; int w2 = pix2 - h2 * NW_;
        const float* cbp = outp + ((size_t)(b2 * NA_ + a2)) * CH_ * NPIX + pix2;

        float xs2[K_], ys2[K_];
        xs2[0] = sigm(cbp[0]);
        ys2[0] = sigm(cbp[NPIX]);
#pragma unroll
        for (int k = 1; k < K_; ++k) {
            xs2[k] = cbp[(size_t)(k + 2) * NPIX];
            ys2[k] = cbp[(size_t)(k + 3) * NPIX];
        }
        float s = 0.0f;
#pragma unroll
        for (int k = 0; k < K_; ++k) {
            float dx = fmaf(xs2[k] + (float)w2, IMW_ / NW_, -trw[1 + 2 * k] * IMW_);
            float dy = fmaf(ys2[k] + (float)h2, IMH_ / NH_, -trw[2 + 2 * k] * IMH_);
            s += conf_term_px(fmaf(dx, dx, dy * dy));
        }
        float conf_t = s * (1.0f / ((7.38905609893065f - 1.0f + EPS_) * 9.0f));
        float diff = cf - conf_t;
        acc_conf = 0.5f * OBJ_ * diff * diff;

        float logits[NC_]; float mxl = -1e30f;
#pragma unroll
        for (int c = 0; c < NC_; ++c) {
            logits[c] = cb[(size_t)(2 * K_ + 1 + c) * NPIX];
            mxl = fmaxf(mxl, logits[c]);
        }
        float se = 0.0f;
#pragma unroll
        for (int c = 0; c < NC_; ++c) se += __builtin_amdgcn_exp2f((logits[c] - mxl) * L2E_);
        int ci = (int)trw[0];
        ci = ci < 0 ? 0 : (ci > NC_ - 1 ? NC_ - 1 : ci);   // JAX gather clamps
        acc_main = 0.5f * lxy + (mxl + __builtin_amdgcn_logf(se) * (1.0f / L2E_) - logits[ci]);
    } else {
        acc_conf = 0.5f * cf * cf * cm0;
    }

    // deterministic block reduction (4 waves)
    float v0 = acc_main, v1 = acc_conf;
#pragma unroll
    for (int off = 32; off > 0; off >>= 1) {
        v0 += __shfl_down(v0, off);
        v1 += __shfl_down(v1, off);
    }
    int wv = tid >> 6;
    if (lane == 0) { s_red[wv] = v0; s_red[4 + wv] = v1; }
    __syncthreads();
    if (tid == 0) {
        float a0 = 0.0f, a1 = 0.0f;
        for (int i = 0; i < 4; ++i) { a0 += s_red[i]; a1 += s_red[4 + i]; }
        // agent-scope RELEASE stores: value reaches the coherent point (not
        // just this XCD's L2) before the counter bump below is observable.
        __hip_atomic_store(&partial[bx * 2],     a0, __ATOMIC_RELEASE,
                           __HIP_MEMORY_SCOPE_AGENT);
        __hip_atomic_store(&partial[bx * 2 + 1], a1, __ATOMIC_RELEASE,
                           __HIP_MEMORY_SCOPE_AGENT);
        __threadfence();
        // mod-NBLK completion count: works for ANY initial counter value (incl.
        // 0xAA poison) since each call adds exactly NBLK and any window of NBLK
        // consecutive values contains exactly one value == NBLK-1 (mod NBLK).
        unsigned int old = __hip_atomic_fetch_add(counter, 1u, __ATOMIC_ACQ_REL,
                                                  __HIP_MEMORY_SCOPE_AGENT);
        s_last = ((old % (unsigned)NBLK) == (unsigned)(NBLK - 1)) ? 1 : 0;
    }
    __syncthreads();

    // last-arriving block: final reduction in FIXED order (deterministic)
    if (s_last) {
        __threadfence();   // acquire side per-thread: invalidate stale L1/L2
        float v0f = 0.0f, v1f = 0.0f;
        for (int i = tid; i < NBLK; i += BLK) {
            v0f += __hip_atomic_load(&partial[2 * i],     __ATOMIC_ACQUIRE,
                                     __HIP_MEMORY_SCOPE_AGENT);
            v1f += __hip_atomic_load(&partial[2 * i + 1], __ATOMIC_ACQUIRE,
                                     __HIP_MEMORY_SCOPE_AGENT);
        }
#pragma unroll
        for (int off = 32; off > 0; off >>= 1) {
            v0f += __shfl_down(v0f, off);
            v1f += __shfl_down(v1f, off);
        }
        __syncthreads();             // s_red reuse safe
        if (lane == 0) { s_red[wv] = v0f; s_red[4 + wv] = v1f; }
        __syncthreads();
        if (tid == 0) {
            float a0 = 0.0f, a1 = 0.0f;
            for (int i = 0; i < 4; ++i) { a0 += s_red[i]; a1 += s_red[4 + i]; }
            loss[0] = a0 + ((epoch[0] > 15) ? a1 : 0.0f);   // PRETRAIN=15
        }
    }
}

} // namespace

extern "C" void kernel_launch(void* const* d_in, const int* in_sizes, int n_in,
                              void* d_out, int out_size, void* d_ws, size_t ws_size,
                              hipStream_t stream)
{
    const float* out_t = (const float*)d_in[0];
    const float* tgt   = (const float*)d_in[1];
    const int*   epoch = (const int*)d_in[2];
    float* loss    = (float*)d_out;
    float* partial = (float*)d_ws;                      // 1280 floats
    unsigned int* counter = (unsigned int*)(partial + 2 * NBLK);

    k_fused<<<NBLK, BLK, 0, stream>>>(out_t, tgt, epoch, loss, partial, counter);
}

// Round 12
// 14.667 us; speedup vs baseline: 2.8212x; 2.8212x over previous
//
#include <hip/hip_runtime.h>
#include <math.h>

namespace {

constexpr int K_   = 9;
constexpr int NC_  = 13;
constexpr int NA_  = 5;
constexpr int NL_  = 21;      // 2K+3
constexpr int NB_  = 32;
constexpr int NH_  = 32;
constexpr int NW_  = 32;
constexpr int NPIX = NH_ * NW_;     // 1024
constexpr int M_   = NA_ * NPIX;    // 5120
constexpr int N_   = NB_ * M_;      // 163840
constexpr int NT_  = 50;
constexpr int CH_  = 2 * K_ + 1 + NC_;  // 32 channels per anchor
constexpr int BLK  = 256;
constexpr int SUBS = M_ / BLK;      // 20 blocks per batch
constexpr int NBLK = NB_ * SUBS;    // 640

constexpr float TH_    = 30.0f;
constexpr float SHARP_ = 2.0f;
constexpr float IMW_   = 640.0f;
constexpr float IMH_   = 480.0f;
constexpr float EPS_   = 1e-5f;
constexpr float OBJ_   = 5.0f;

constexpr float L2E_  = 1.4426950408889634f;
constexpr float CC1_  = -(SHARP_ / TH_) * L2E_;   // slope per pixel-distance, log2 domain
constexpr float CC2_  = SHARP_ * L2E_;            // offset, log2 domain
// 0.6 * ((e^2-1)+eps) * 9 : sum-domain silence threshold.
// A target with 2-D close-count c has sum <= c*(e^2-1)=6.389c; c<=5 -> 31.95 < 34.50,
// so only targets with 2-D cnt>=6 can trip (cur > SIL).
constexpr float SUMTHR_ = 34.500957f;
constexpr float WSLACK_ = TH_ + 4.0f;   // window slack: 30 + fp/half-rounding margin

typedef _Float16 h2v __attribute__((ext_vector_type(2)));

__device__ __constant__ float c_aw[5] = {1.482f, 2.0501f, 2.3946f, 3.1018f, 3.4879f};
__device__ __constant__ float c_ah[5] = {2.2412f, 3.1265f, 4.6891f, 3.991f, 5.2505f};

__device__ __forceinline__ float sigm(float x) {
    return 1.0f / (1.0f + __builtin_amdgcn_exp2f(-L2E_ * x));
}

// corner-conf term, pixel-domain d2: exp(SHARP*(1-d/TH)) - 1, masked to d<TH
__device__ __forceinline__ float conf_term_px(float d2) {
    float e = __builtin_amdgcn_exp2f(fmaf(__builtin_amdgcn_sqrtf(d2), CC1_, CC2_)) - 1.0f;
    return (d2 < TH_ * TH_) ? e : 0.0f;
}

__device__ __forceinline__ h2v h2min(h2v a, h2v b) {
#if __has_builtin(__builtin_elementwise_min)
    return __builtin_elementwise_min(a, b);
#else
    h2v r;
    r[0] = a[0] < b[0] ? a[0] : b[0];
    r[1] = a[1] < b[1] ? a[1] : b[1];
    return r;
#endif
}

// ---------------- Kernel 1: fused targets + screen + per-cell losses ----------
__global__ __launch_bounds__(BLK) void k_fused(
        const float* __restrict__ outp,
        const float* __restrict__ tgt,
        float* __restrict__ partial)
{
    __shared__ float s_t[NT_ * NL_];    // whole target slab for this batch
    __shared__ int   s_win[BLK];
    __shared__ int   s_nv;
    __shared__ float s_red[8];

    int bx  = blockIdx.x;
    int b   = bx / SUBS, sub = bx - b * SUBS;
    int tid = threadIdx.x;
    int lane = tid & 63;

    // ---- issue per-cell global loads FIRST: latency overlaps staging/ballots
    int m = sub * BLK + tid;
    int a = m / NPIX;  int pix = m - a * NPIX;   // a uniform per block (BLK | NPIX)
    int h = pix >> 5;  int w   = pix & 31;
    const float* cb = outp + ((size_t)(b * NA_ + a)) * CH_ * NPIX + pix;

    float yraw[K_];
    yraw[0] = cb[NPIX];
#pragma unroll
    for (int k = 1; k < K_; ++k) yraw[k] = cb[(size_t)(k + 3) * NPIX];
    float cfraw = cb[(size_t)(2 * K_) * NPIX];   // channel 18

    // ---- stage target slab
    const float* tb = tgt + (size_t)b * NT_ * NL_;
    s_win[tid] = -1;
    for (int i = tid; i < NT_ * NL_; i += BLK) s_t[i] = tb[i];
    __syncthreads();

    if (tid < 64) {   // wave 0: validity prefix via ballot
        float x0 = (tid < NT_) ? s_t[tid * NL_ + 1] : 0.0f;
        unsigned long long mk = __ballot(tid < NT_ && x0 != 0.0f);
        if (tid == 0) s_nv = (int)__builtin_ctzll((~mk) | (1ull << NT_));
    }
    __syncthreads();
    int nv = s_nv;

    // per-target flat + win scatter (recomputed per block; 50 lanes, cheap)
    if (tid < nv) {
        const float* row = &s_t[tid * NL_];
        int gi0 = (int)(row[1] * (float)NW_);
        int gj0 = (int)(row[2] * (float)NH_);
        float gw = row[NL_ - 2] * (float)NW_;
        float gh = row[NL_ - 1] * (float)NH_;
        float best_iou = 0.0f; int best_n = -1;
#pragma unroll
        for (int a2 = 0; a2 < NA_; ++a2) {
            float cw  = fminf(c_aw[a2], gw);
            float chh = fminf(c_ah[a2], gh);
            float iou = 0.0f;
            if (cw > 0.0f && chh > 0.0f) {
                float inter = cw * chh;
                iou = inter / (c_aw[a2] * c_ah[a2] + gw * gh - inter);
            }
            if (iou > best_iou) { best_iou = iou; best_n = a2; }
        }
        int bn = ((best_n % NA_) + NA_) % NA_;   // Python -1 % 5 == 4
        int flat = ((b * NA_ + bn) * NH_ + gj0) * NW_ + gi0;
        int rel = flat - b * M_ - sub * BLK;
        if (rel >= 0 && rel < BLK) atomicMax(&s_win[rel], tid);  // last(=max) t wins
    }
    __syncthreads();

    // y channels (raw kept for hit path), qy in pixel domain
    float ysv[K_], qy[K_];
    ysv[0] = sigm(yraw[0]);
#pragma unroll
    for (int k = 1; k < K_; ++k) ysv[k] = yraw[k];
#pragma unroll
    for (int k = 0; k < K_; ++k) qy[k] = (ysv[k] + (float)h) * (IMH_ / NH_);

    // per-wave min/max of qy[k]: packed-half butterfly (mn, -mx) via pk_min
    h2v pk[K_];
#pragma unroll
    for (int k = 0; k < K_; ++k) {
        pk[k][0] = (_Float16)qy[k];
        pk[k][1] = (_Float16)(-qy[k]);
    }
#pragma unroll
    for (int off = 1; off < 64; off <<= 1) {
#pragma unroll
        for (int k = 0; k < K_; ++k) {
            unsigned u; __builtin_memcpy(&u, &pk[k], 4);
            u = __shfl_xor(u, off);
            h2v o; __builtin_memcpy(&o, &u, 4);
            pk[k] = h2min(pk[k], o);
        }
    }
    float mnw[K_], mxw[K_];
#pragma unroll
    for (int k = 0; k < K_; ++k) {
        mnw[k] = (float)pk[k][0] - WSLACK_;
        mxw[k] = -(float)pk[k][1] + WSLACK_;
    }

    // layer 1: wave-uniform survivor ballot (lane t checks target t)
    int wcnt = 0;
    if (lane < NT_) {
        const float* tr = &s_t[lane * NL_];
#pragma unroll
        for (int k = 0; k < K_; ++k) {
            float gy = tr[2 + 2 * k] * IMH_;
            wcnt += (gy >= mnw[k] && gy <= mxw[k]) ? 1 : 0;
        }
    }
    unsigned long long smask = __ballot(lane < NT_ && wcnt >= 6);
    smask &= (nv >= 64) ? ~0ull : ((1ull << nv) - 1);   // valid-prefix targets only

    // layer 2: per-lane y-cnt>=6 over survivors -> per-lane candidate mask
    unsigned long long candm = 0;
    unsigned long long mm = smask;
    while (mm) {
        int t = (int)__builtin_ctzll(mm); mm &= mm - 1;
        const float* tr = &s_t[t * NL_];   // uniform addr -> LDS broadcast
        int cnt = 0;
#pragma unroll
        for (int k = 0; k < K_; ++k) {
            float dy = tr[2 + 2 * k] * IMH_ - qy[k];
            cnt += (fabsf(dy) < TH_) ? 1 : 0;
        }
        if (cnt >= 6) candm |= 1ull << t;
    }

    float cm0 = 1.0f;
    if (candm) {   // ~1% of lanes: 2-D refine, then (astronomically rare) exact
        float qx[K_];
        qx[0] = (sigm(cb[0]) + (float)w) * (IMW_ / NW_);
#pragma unroll
        for (int k = 1; k < K_; ++k)
            qx[k] = (cb[(size_t)(k + 2) * NPIX] + (float)w) * (IMW_ / NW_);

        unsigned long long hot = 0, m2 = candm;
        while (m2) {
            int t = (int)__builtin_ctzll(m2); m2 &= m2 - 1;
            const float* tr = &s_t[t * NL_];
            int cnt = 0;
#pragma unroll
            for (int k = 0; k < K_; ++k) {
                float dx = tr[1 + 2 * k] * IMW_ - qx[k];
                float dy = tr[2 + 2 * k] * IMH_ - qy[k];
                float d2 = fmaf(dx, dx, dy * dy);
                cnt += (d2 < TH_ * TH_) ? 1 : 0;
            }
            if (cnt >= 6) hot |= 1ull << t;
        }
        if (hot) {   // exact sum only over targets that can possibly trip SIL
            float ms = 0.0f;
            while (hot) {
                int t = (int)__builtin_ctzll(hot); hot &= hot - 1;
                const float* tr = &s_t[t * NL_];
                float s = 0.0f;
#pragma unroll
                for (int k = 0; k < K_; ++k) {
                    float dx = tr[1 + 2 * k] * IMW_ - qx[k];
                    float dy = tr[2 + 2 * k] * IMH_ - qy[k];
                    s += conf_term_px(fmaf(dx, dx, dy * dy));
                }
                ms = fmaxf(ms, s);
            }
            cm0 = (ms > SUMTHR_) ? 0.0f : 1.0f;
        }
    }

    // per-cell losses
    float cf = sigm(cfraw);
    int win = s_win[tid];
    float acc_main = 0.0f, acc_conf = 0.0f;
    if (win >= 0) {                                  // hit path (~2.5 lanes/block)
        const float* trw = &s_t[win * NL_];
        int gi0 = (int)(trw[1] * (float)NW_);
        int gj0 = (int)(trw[2] * (float)NH_);

        float xsv[K_];
        xsv[0] = sigm(cb[0]);
#pragma unroll
        for (int k = 1; k < K_; ++k) xsv[k] = cb[(size_t)(k + 2) * NPIX];

        float lxy = 0.0f;
#pragma unroll
        for (int k = 0; k < K_; ++k) {
            float tx = trw[1 + 2 * k] * (float)NW_ - (float)gi0;
            float ty = trw[2 + 2 * k] * (float)NH_ - (float)gj0;
            float ddx = xsv[k] - tx;
            float ddy = ysv[k] - ty;
            lxy += ddx * ddx + ddy * ddy;
        }

        // conf_t: gather prediction at pb = (b*M - nPix + gj0*nW + gi0) mod N
        long long pbl = (long long)b * M_ - NPIX + gj0 * NW_ + gi0;
        int pb = (int)(((pbl % N_) + N_) % N_);
        int b2 = pb / M_;   int m2i  = pb - b2 * M_;
        int a2 = m2i / NPIX; int pix2 = m2i - a2 * NPIX;
        int h2 = pix2 / NW_; int w2 = pix2 - h2 * NW_;
        const float* cbp = outp + ((size_t)(b2 * NA_ + a2)) * CH_ * NPIX + pix2;

        float xs2[K_], ys2[K_];
        xs2[0] = sigm(cbp[0]);
        ys2[0] = sigm(cbp[NPIX]);
#pragma unroll
        for (int k = 1; k < K_; ++k) {
            xs2[k] = cbp[(size_t)(k + 2) * NPIX];
            ys2[k] = cbp[(size_t)(k + 3) * NPIX];
        }
        float s = 0.0f;
#pragma unroll
        for (int k = 0; k < K_; ++k) {
            float dx = fmaf(xs2[k] + (float)w2, IMW_ / NW_, -trw[1 + 2 * k] * IMW_);
            float dy = fmaf(ys2[k] + (float)h2, IMH_ / NH_, -trw[2 + 2 * k] * IMH_);
            s += conf_term_px(fmaf(dx, dx, dy * dy));
        }
        float conf_t = s * (1.0f / ((7.38905609893065f - 1.0f + EPS_) * 9.0f));
        float diff = cf - conf_t;
        acc_conf = 0.5f * OBJ_ * diff * diff;

        float logits[NC_]; float mxl = -1e30f;
#pragma unroll
        for (int c = 0; c < NC_; ++c) {
            logits[c] = cb[(size_t)(2 * K_ + 1 + c) * NPIX];
            mxl = fmaxf(mxl, logits[c]);
        }
        float se = 0.0f;
#pragma unroll
        for (int c = 0; c < NC_; ++c) se += __builtin_amdgcn_exp2f((logits[c] - mxl) * L2E_);
        int ci = (int)trw[0];
        ci = ci < 0 ? 0 : (ci > NC_ - 1 ? NC_ - 1 : ci);   // JAX gather clamps
        acc_main = 0.5f * lxy + (mxl + __builtin_amdgcn_logf(se) * (1.0f / L2E_) - logits[ci]);
    } else {
        acc_conf = 0.5f * cf * cf * cm0;
    }

    // deterministic block reduction (4 waves)
    float v0 = acc_main, v1 = acc_conf;
#pragma unroll
    for (int off = 32; off > 0; off >>= 1) {
        v0 += __shfl_down(v0, off);
        v1 += __shfl_down(v1, off);
    }
    int wv = tid >> 6;
    if (lane == 0) { s_red[wv] = v0; s_red[4 + wv] = v1; }
    __syncthreads();
    if (tid == 0) {
        float a0 = 0.0f, a1 = 0.0f;
        for (int i = 0; i < 4; ++i) { a0 += s_red[i]; a1 += s_red[4 + i]; }
        partial[bx * 2]     = a0;
        partial[bx * 2 + 1] = a1;
    }
}

// ---------------- Kernel 2: final reduction + epoch gate ----------------------
__global__ __launch_bounds__(256) void k_final(const float* __restrict__ partial,
                                               const int* __restrict__ epoch,
                                               float* __restrict__ outp)
{
    __shared__ float s_red[8];
    int tid = threadIdx.x;
    float v0 = 0.0f, v1 = 0.0f;
    const float2* p2 = (const float2*)partial;
    for (int i = tid; i < NBLK; i += 256) {
        float2 v = p2[i];
        v0 += v.x;
        v1 += v.y;
    }
#pragma unroll
    for (int off = 32; off > 0; off >>= 1) {
        v0 += __shfl_down(v0, off);
        v1 += __shfl_down(v1, off);
    }
    int lane = tid & 63, wv = tid >> 6;
    if (lane == 0) { s_red[wv] = v0; s_red[4 + wv] = v1; }
    __syncthreads();
    if (tid == 0) {
        float a0 = 0.0f, a1 = 0.0f;
        for (int i = 0; i < 4; ++i) { a0 += s_red[i]; a1 += s_red[4 + i]; }
        outp[0] = a0 + ((epoch[0] > 15) ? a1 : 0.0f);   // PRETRAIN=15
    }
}

} // namespace

extern "C" void kernel_launch(void* const* d_in, const int* in_sizes, int n_in,
                              void* d_out, int out_size, void* d_ws, size_t ws_size,
                              hipStream_t stream)
{
    const float* out_t = (const float*)d_in[0];
    const float* tgt   = (const float*)d_in[1];
    const int*   epoch = (const int*)d_in[2];
    float* loss = (float*)d_out;

    float* partial = (float*)d_ws;    // 1280 floats

    k_fused<<<NBLK, BLK, 0, stream>>>(out_t, tgt, partial);
    k_final<<<1, 256, 0, stream>>>(partial, epoch, loss);
}